// Round 9
// baseline (110.239 us; speedup 1.0000x reference)
//
#include <hip/hip_runtime.h>
#include <cstddef>
#include <cstdint>

#define L_SEQ 2048
#define DM    1024
#define NREC  8

typedef __attribute__((ext_vector_type(8))) short short8;
typedef __attribute__((ext_vector_type(4))) float f32x4;
typedef __attribute__((ext_vector_type(2))) unsigned int u32x2;

__device__ inline unsigned short f2bf(float f) {
    unsigned u = __float_as_uint(f);
    unsigned r = (u + 0x7FFFu + ((u >> 16) & 1u)) >> 16;
    return (unsigned short)r;
}
__device__ inline float bf2f(unsigned short s) {
    return __uint_as_float(((unsigned)s) << 16);
}
__device__ inline void gload_lds16(const void* g, void* l) {
    __builtin_amdgcn_global_load_lds(
        (const __attribute__((address_space(1))) void*)g,
        (__attribute__((address_space(3))) void*)l, 16, 0, 0);
}
__device__ inline short8 pack8(f32x4 x, f32x4 y) {
    short8 c;
    c[0] = (short)f2bf(x[0]); c[1] = (short)f2bf(x[1]);
    c[2] = (short)f2bf(x[2]); c[3] = (short)f2bf(x[3]);
    c[4] = (short)f2bf(y[0]); c[5] = (short)f2bf(y[1]);
    c[6] = (short)f2bf(y[2]); c[7] = (short)f2bf(y[3]);
    return c;
}

// ======== fused-cvt 128x128 GEMM: klin[b][h][l] = W[h][:].u[b][l][:] + bias
// 4 waves (2M x 2N), BK=32, 2-deep LDS dbuf (32 KB), 1024 blocks, 3 blocks/CU
// (launch_bounds(256,3)) so co-resident blocks hide each other's per-tile
// barrier + load latency (r8's 256^2 was 1 block/CU -> 17% occ -> exposed).
// Reg-staged fused conversion (T14): issue next tile's 8 f32x4 at tile top,
// compute current tile (16 MFMA, setprio), then cvt+swizzled ds_write late.
// LDS swizzle (proven 0-conflict r6-r8): pair p=row>>1 holds 8 granules
// (128B); logical g=(row&1)*4+slot; phys = g ^ (p&7). Staging: thread covers
// row sr=tid>>1, k-half hf=tid&1 -> logical granules g0=(sr&1)*4+2hf, g0+1.
// Fragment read foff identical to r6/r7/r8.
__global__ __launch_bounds__(256, 3) void gemm_fused(
    const float* __restrict__ Wf, const float* __restrict__ uf,
    const float* __restrict__ bias, unsigned short* __restrict__ klin)
{
    __shared__ unsigned short As[2][128 * 32];   // 2 x 8 KB
    __shared__ unsigned short Bs[2][128 * 32];   // 2 x 8 KB

    // XCD-contiguous: XCD x gets wg in [128x,128x+128) = one whole batch;
    // h innermost: 8 consecutive wgs share one u l-panel (512 KB, L2-hot).
    int wg = (int)blockIdx.x;
    wg = (wg & 7) * 128 + (wg >> 3);
    const int b    = wg >> 7;
    const int rest = wg & 127;
    const int h0 = (rest & 7) * 128;
    const int l0 = (rest >> 3) * 128;
    const int tid = (int)threadIdx.x;
    const int lane = tid & 63, wv = tid >> 6;

    // staging: thread covers row sr (both operands), k-half hf (16 f32)
    const int sr = tid >> 1;          // 0..127
    const int hf = tid & 1;
    const int p  = sr >> 1;
    const int g0 = (sr & 1) * 4 + 2 * hf;
    const int w0off = p * 128 + ((g0)     ^ (p & 7)) * 16;
    const int w1off = p * 128 + ((g0 + 1) ^ (p & 7)) * 16;

    const float* gA = Wf + (size_t)(h0 + sr) * DM + hf * 16;
    const float* gB = uf + ((size_t)b * L_SEQ + l0 + sr) * DM + hf * 16;

    const int wm = wv >> 1, wn = wv & 1;
    const int lr = lane & 15, lk = lane >> 4;
    const int foff = (lr >> 1) * 128 + ((((lr & 1) << 2) + lk) ^ (lr >> 1)) * 16;

    f32x4 acc[4][4];
    #pragma unroll
    for (int m = 0; m < 4; ++m)
        #pragma unroll
        for (int n = 0; n < 4; ++n) acc[m][n] = (f32x4){0.f, 0.f, 0.f, 0.f};

    // prologue: stage tile 0
    {
        f32x4 a0 = *(const f32x4*)(gA),      a1 = *(const f32x4*)(gA + 4);
        f32x4 a2 = *(const f32x4*)(gA + 8),  a3 = *(const f32x4*)(gA + 12);
        f32x4 b0 = *(const f32x4*)(gB),      b1 = *(const f32x4*)(gB + 4);
        f32x4 b2 = *(const f32x4*)(gB + 8),  b3 = *(const f32x4*)(gB + 12);
        *(short8*)((char*)&As[0][0] + w0off) = pack8(a0, a1);
        *(short8*)((char*)&As[0][0] + w1off) = pack8(a2, a3);
        *(short8*)((char*)&Bs[0][0] + w0off) = pack8(b0, b1);
        *(short8*)((char*)&Bs[0][0] + w1off) = pack8(b2, b3);
    }
    __syncthreads();

    #pragma unroll 1
    for (int t = 0; t < 32; ++t) {
        const int cur = t & 1;
        const char* Ab = (const char*)&As[cur][0];
        const char* Bb = (const char*)&Bs[cur][0];
        f32x4 a0, a1, a2, a3, b0, b1, b2, b3;
        if (t < 31) {   // issue next-tile loads early (T14 split)
            const int ko = (t + 1) * 32;
            a0 = *(const f32x4*)(gA + ko);     a1 = *(const f32x4*)(gA + ko + 4);
            a2 = *(const f32x4*)(gA + ko + 8); a3 = *(const f32x4*)(gA + ko + 12);
            b0 = *(const f32x4*)(gB + ko);     b1 = *(const f32x4*)(gB + ko + 4);
            b2 = *(const f32x4*)(gB + ko + 8); b3 = *(const f32x4*)(gB + ko + 12);
        }
        short8 af[4], bfr[4];
        #pragma unroll
        for (int n = 0; n < 4; ++n)
            bfr[n] = *(const short8*)(Bb + (wn * 64 + n * 16) * 64 + foff);
        #pragma unroll
        for (int m = 0; m < 4; ++m)
            af[m] = *(const short8*)(Ab + (wm * 64 + m * 16) * 64 + foff);
        __builtin_amdgcn_s_setprio(1);
        #pragma unroll
        for (int m = 0; m < 4; ++m)
            #pragma unroll
            for (int n = 0; n < 4; ++n)
                acc[m][n] = __builtin_amdgcn_mfma_f32_16x16x32_bf16(af[m], bfr[n], acc[m][n], 0, 0, 0);
        __builtin_amdgcn_s_setprio(0);
        __builtin_amdgcn_sched_barrier(0);   // keep cvt (and its vmcnt wait) after MFMAs
        if (t < 31) {
            char* An = (char*)&As[cur ^ 1][0];
            char* Bn = (char*)&Bs[cur ^ 1][0];
            *(short8*)(An + w0off) = pack8(a0, a1);
            *(short8*)(An + w1off) = pack8(a2, a3);
            *(short8*)(Bn + w0off) = pack8(b0, b1);
            *(short8*)(Bn + w1off) = pack8(b2, b3);
            __syncthreads();
        }
    }

    // epilogue: D row=(lane>>4)*4+reg (h), col=lane&15 (l)
    #pragma unroll
    for (int m = 0; m < 4; ++m) {
        const int h = h0 + wm * 64 + m * 16 + lk * 4;
        #pragma unroll
        for (int n = 0; n < 4; ++n) {
            const int l = l0 + wn * 64 + n * 16 + lr;
            #pragma unroll
            for (int r = 0; r < 4; ++r) {
                float v = acc[m][n][r] + bias[h + r];
                klin[((size_t)b * DM + h + r) * L_SEQ + l] = f2bf(v);
            }
        }
    }
}

// ---------------- expand: one block per (h, b-pair); 29.7KB LDS (unchanged) ----
__device__ inline void get_disc(const float* __restrict__ log_dt,
                                const float* __restrict__ lar,
                                const float* __restrict__ aim, int h, int n,
                                float& Are, float& Aim, float& lre, float& lim)
{
    float dtv = expf(log_dt[h]);
    Are = -expf(lar[h * 64 + n]);
    Aim = aim[h * 64 + n];
    lre = dtv * Are;
    lim = dtv * Aim;
}

__global__ __launch_bounds__(256, 5) void expand(
    const unsigned short* __restrict__ klin,
    const float* __restrict__ shift_B, const float* __restrict__ shift_C,
    const float* __restrict__ ssm_k_D, const float* __restrict__ log_dt,
    const float* __restrict__ log_A_real, const float* __restrict__ A_imag,
    const float* __restrict__ B_re, const float* __restrict__ B_im,
    float* __restrict__ out)
{
    __shared__ __align__(16) char sm[29696];
    constexpr int OKL = 0;
    constexpr int OKK = 8704;
    constexpr int OAF = 16896;
    constexpr int OPR = 20224;
    constexpr int OPI = 24320;
    constexpr int OF  = 28416;
    constexpr int OBS = 28672;
    constexpr int OCS = 28928;
    constexpr int OW32 = 29184;

    const int h  = blockIdx.x;
    const int bg = blockIdx.y;
    const int t = threadIdx.x;
    const int lane = t & 63, wv = t >> 6;

    if (t < 32) {
        int rl = t >> 4, reg = (t >> 3) & 1, idx = t & 7;
        *(f32x4*)&sm[OKL + rl * 4352 + reg * 4224 + idx * 16] = (f32x4){0.f, 0.f, 0.f, 0.f};
    }
    {
        const int rl = wv >> 1, hf = wv & 1;
        const int b = bg * 2 + rl;
        const char* krow = (const char*)(klin + ((size_t)b * DM + h) * L_SEQ);
        const int s = (2 * rl + 1 + (lane >> 3)) & 7;
        const int so = hf * 2048 + (lane >> 3) * 128 + ((lane ^ s) & 7) * 16;
        gload_lds16(krow + so,        &sm[OKL + rl * 4352 + 128 + hf * 2048]);
        gload_lds16(krow + so + 1024, &sm[OKL + rl * 4352 + 128 + hf * 2048 + 1024]);
    }
    if (t < 64) {
        ((float*)&sm[OBS])[t] = shift_B[h * 64 + t];
        ((float*)&sm[OCS])[t] = shift_C[h * 64 + t];
        float Are, Aim, lre, lim;
        get_disc(log_dt, log_A_real, A_imag, h, t, Are, Aim, lre, lim);
        float er = expf(32.f * lre);
        float sn, cs; sincosf(32.f * lim, &sn, &cs);
        ((float*)&sm[OW32])[t * 2]     = er * cs;
        ((float*)&sm[OW32])[t * 2 + 1] = er * sn;
    }
    {
        int n = t >> 2, s4 = t & 3;
        float Are, Aim, lre, lim;
        get_disc(log_dt, log_A_real, A_imag, h, n, Are, Aim, lre, lim);
        float erw = expf(lre), snw, csw;
        sincosf(lim, &snw, &csw);
        float wr = erw * csw, wi = erw * snw;
        float e0 = (float)(24 - 8 * s4);
        float mag = expf(e0 * lre);
        float sn0, cs0; sincosf(e0 * lim, &sn0, &cs0);
        float pr = mag * cs0, pi = mag * sn0;
        float vr[8], vi[8];
        vr[7] = pr; vi[7] = pi;
        #pragma unroll
        for (int k = 6; k >= 0; --k) {
            float nr = pr * wr - pi * wi;
            pi = fmaf(pr, wi, pi * wr);
            pr = nr;
            vr[k] = pr; vi[k] = pi;
        }
        short8 re8, im8;
        #pragma unroll
        for (int e = 0; e < 8; ++e) {
            re8[e] = (short)f2bf(vr[e]);
            im8[e] = (short)f2bf(vi[e]);
        }
        *(short8*)&sm[OPR + t * 16] = re8;
        *(short8*)&sm[OPI + t * 16] = im8;
    }
    __syncthreads();   // B1

    if (t < 64) {
        const float* Bp = (const float*)&sm[OBS];
        const float* Cp = (const float*)&sm[OCS];
        float f = (t == 0) ? ssm_k_D[h] : 0.f;
        #pragma unroll 8
        for (int j = 0; j < 64; ++j) {
            float cv = Cp[(j + t) & 63];
            f = fmaf((j + t < 64) ? cv : 0.f, Bp[j], f);
        }
        ((float*)&sm[OF])[t] = f;
    }
    __syncthreads();   // B2

    {
        int i = t >> 4, ks = t & 15;
        if (ks < 12) {
            const float* Fp = (const float*)&sm[OF];
            short8 row;
            #pragma unroll
            for (int e = 0; e < 8; ++e) {
                int k = ks * 8 + e;
                int m = 64 + i - k;
                float v = (m >= 0 && m < 64) ? Fp[m] : 0.f;
                row[e] = (short)f2bf(v);
            }
            *(short8*)&sm[OAF + i * 208 + ks * 16] = row;
        }
    }
    __syncthreads();   // B3

    {
        short8 afr[3];
        #pragma unroll
        for (int ks = 0; ks < 3; ++ks)
            afr[ks] = *(const short8*)&sm[OAF + (lane & 15) * 208 + ks * 64 + (lane >> 4) * 16];
        const int rl = wv >> 1;
        const int jbase = (wv & 1) * 4;
        #pragma unroll
        for (int jj = 0; jj < 4; ++jj) {
            const int jg = jbase + jj;
            f32x4 d = (f32x4){0.f, 0.f, 0.f, 0.f};
            #pragma unroll
            for (int ks = 0; ks < 3; ++ks) {
                int o = rl * 4352 + (jg * 256 + (lane & 15) * 16 + ks * 32 + (lane >> 4) * 8) * 2;
                o ^= ((o >> 7) & 7) << 4;     // SWL
                short8 bfrag = *(const short8*)&sm[OKL + o];
                d = __builtin_amdgcn_mfma_f32_16x16x32_bf16(afr[ks], bfrag, d, 0, 0, 0);
            }
            unsigned pk0 = ((unsigned)f2bf(d[0])) | (((unsigned)f2bf(d[1])) << 16);
            unsigned pk1 = ((unsigned)f2bf(d[2])) | (((unsigned)f2bf(d[3])) << 16);
            int o2 = rl * 4096 + jg * 512 + (lane & 15) * 32 + (lane >> 4) * 8;
            o2 ^= ((o2 >> 9) & 7) << 4;       // SWK
            *(u32x2*)&sm[OKK + o2] = (u32x2){pk0, pk1};
        }
    }
    __syncthreads();   // B4

    {
        const int mt = wv;
        short8 par = *(const short8*)&sm[OPR + (mt * 16 + (lane & 15)) * 64 + (lane >> 4) * 16];
        short8 pai = *(const short8*)&sm[OPI + (mt * 16 + (lane & 15)) * 64 + (lane >> 4) * 16];
        float w32r[4], w32i[4];
        #pragma unroll
        for (int rg = 0; rg < 4; ++rg) {
            int n = mt * 16 + (lane >> 4) * 4 + rg;
            float2 ww = *(const float2*)&sm[OW32 + n * 8];
            w32r[rg] = ww.x;
            w32i[rg] = ww.y;
        }
        f32x4 cr = (f32x4){0.f, 0.f, 0.f, 0.f};
        f32x4 ci_ = (f32x4){0.f, 0.f, 0.f, 0.f};
        const int colb = (lane & 15) >> 3;
        const int colr = lane & 7;
        #pragma unroll
        for (int g2 = 0; g2 < 8; ++g2) {
            int o = colb * 4096 + colr * 512 + g2 * 64 + (lane >> 4) * 16;
            o ^= ((o >> 9) & 7) << 4;         // SWK
            short8 kf = *(const short8*)&sm[OKK + o];
            f32x4 sre = __builtin_amdgcn_mfma_f32_16x16x32_bf16(par, kf, (f32x4){0.f,0.f,0.f,0.f}, 0, 0, 0);
            f32x4 sim = __builtin_amdgcn_mfma_f32_16x16x32_bf16(pai, kf, (f32x4){0.f,0.f,0.f,0.f}, 0, 0, 0);
            #pragma unroll
            for (int rg = 0; rg < 4; ++rg) {
                float wr = w32r[rg], wi = w32i[rg];
                float ncr = fmaf(cr[rg], wr, fmaf(-ci_[rg], wi, sre[rg]));
                float nci = fmaf(cr[rg], wi, fmaf(ci_[rg], wr, sim[rg]));
                cr[rg] = ncr;
                ci_[rg] = nci;
            }
        }
        __syncthreads();   // B5
        #pragma unroll
        for (int rg = 0; rg < 4; ++rg) {
            int n = mt * 16 + (lane >> 4) * 4 + rg;
            int c = lane & 15;
            ((float*)&sm[OKK])[n * 17 + c] = cr[rg];
            ((float*)&sm[OKK])[1088 + n * 17 + c] = ci_[rg];
        }
    }
    __syncthreads();   // B6

    if (t < 128) {
        const int n = t & 63, bl = t >> 6;
        const int b = bg * 2 + bl;
        float Are, Aim, lre, lim;
        get_disc(log_dt, log_A_real, A_imag, h, n, Are, Aim, lre, lim);
        float er = expf(lre), sn, cs;
        sincosf(lim, &sn, &cs);
        float wr = er * cs, wi = er * sn;
        float2 w32v = *(const float2*)&sm[OW32 + n * 8];
        float ar = w32v.x, ai = w32v.y;
        #pragma unroll
        for (int s = 0; s < 3; ++s) {
            float nr = ar * ar - ai * ai;
            ai = 2.f * ar * ai;
            ar = nr;
        }
        float den = Are * Are + Aim * Aim;
        float wm1r = wr - 1.f, wm1i = wi;
        float tr_ = (wm1r * Are + wm1i * Aim) / den;
        float ti_ = (wm1i * Are - wm1r * Aim) / den;
        float br = B_re[h * 64 + n], bi = B_im[h * 64 + n];
        float dBr = br * tr_ - bi * ti_;
        float dBi = br * ti_ + bi * tr_;
        const float* cre = (const float*)&sm[OKK] + n * 17 + bl * 8;
        const float* cim = (const float*)&sm[OKK] + 1088 + n * 17 + bl * 8;
        float sr = 0.f, si_ = 0.f;
        #pragma unroll
        for (int r = 0; r < 8; ++r) {
            float nsr = fmaf(ar, sr, fmaf(-ai, si_, cre[r]));
            float nsi = fmaf(ar, si_, fmaf(ai, sr, cim[r]));
            sr = nsr; si_ = nsi;
            out[(((size_t)b * NREC + r) * DM + h) * 64 + n] = dBr * sr - dBi * si_;
        }
    }
}

extern "C" void kernel_launch(void* const* d_in, const int* in_sizes, int n_in,
                              void* d_out, int out_size, void* d_ws, size_t ws_size,
                              hipStream_t stream)
{
    const float* u       = (const float*)d_in[0];
    const float* W       = (const float*)d_in[1];
    const float* bias    = (const float*)d_in[2];
    const float* shift_B = (const float*)d_in[3];
    const float* shift_C = (const float*)d_in[4];
    const float* ssm_k_D = (const float*)d_in[5];
    const float* log_dt  = (const float*)d_in[6];
    const float* log_Ar  = (const float*)d_in[7];
    const float* A_imag  = (const float*)d_in[8];
    const float* B_re    = (const float*)d_in[9];
    const float* B_im    = (const float*)d_in[10];
    float* out = (float*)d_out;

    unsigned short* klin = (unsigned short*)d_ws;   // 32 MB

    gemm_fused<<<dim3(1024), 256, 0, stream>>>(W, u, bias, klin);

    expand<<<dim3(DM, 4), 256, 0, stream>>>(klin, shift_B, shift_C, ssm_k_D, log_dt,
                                            log_Ar, A_imag, B_re, B_im, out);
}

// Round 10
// 98.487 us; speedup vs baseline: 1.1193x; 1.1193x over previous
//
#include <hip/hip_runtime.h>
#include <cstddef>
#include <cstdint>

#define L_SEQ 2048
#define DM    1024
#define NREC  8

typedef __attribute__((ext_vector_type(8))) short short8;
typedef __attribute__((ext_vector_type(4))) float f32x4;
typedef __attribute__((ext_vector_type(2))) unsigned int u32x2;

__device__ inline unsigned short f2bf(float f) {
    unsigned u = __float_as_uint(f);
    unsigned r = (u + 0x7FFFu + ((u >> 16) & 1u)) >> 16;
    return (unsigned short)r;
}
__device__ inline float bf2f(unsigned short s) {
    return __uint_as_float(((unsigned)s) << 16);
}
__device__ inline void gload_lds16(const void* g, void* l) {
    __builtin_amdgcn_global_load_lds(
        (const __attribute__((address_space(1))) void*)g,
        (__attribute__((address_space(3))) void*)l, 16, 0, 0);
}
__device__ inline short8 pack8(f32x4 x, f32x4 y) {
    short8 c;
    c[0] = (short)f2bf(x[0]); c[1] = (short)f2bf(x[1]);
    c[2] = (short)f2bf(x[2]); c[3] = (short)f2bf(x[3]);
    c[4] = (short)f2bf(y[0]); c[5] = (short)f2bf(y[1]);
    c[6] = (short)f2bf(y[2]); c[7] = (short)f2bf(y[3]);
    return c;
}

// ======== fused-cvt 256x128 GEMM: klin[b][h][l] = W[h][:].u[b][l][:] + bias
// r8's proven-stable 512-thread fused structure (VGPR=104 there: staging regs
// HELD, loads issue early) with the tile split changed 256x256 -> 256x128:
// grid 512 = 2 independent blocks/CU (the r8 failure was grid 256 = 1/CU,
// no cross-block latency hiding), 4 waves/SIMD via __launch_bounds__(512,4).
// 8 waves as 4M x 2N (wave tile 64x64, acc[4][4]=64 VGPR, 16 MFMA/tile).
// Reg-staged fused conversion (T14): issue next tile's 6 f32x4 at tile top,
// MFMA cluster (setprio), then cvt+swizzled ds_write late; sched_barrier
// pins the cvt (and its vmcnt wait) after the MFMAs.
// LDS swizzle (proven 0-conflict r6-r9): pair p=row>>1 holds 8 x 16B granules
// (128B = all 32 banks); logical g=(row&1)*4+slot; phys = g ^ (p&7).
// Fragment read foff byte-identical to r6-r9.
__global__ __launch_bounds__(512, 4) void gemm_fused(
    const float* __restrict__ Wf, const float* __restrict__ uf,
    const float* __restrict__ bias, unsigned short* __restrict__ klin)
{
    __shared__ unsigned short As[2][256 * 32];   // 2 x 16 KB
    __shared__ unsigned short Bs[2][128 * 32];   // 2 x 8 KB

    // XCD-contiguous: XCD x gets wg in [64x, 64x+64) = one whole batch;
    // h innermost: 4 consecutive wgs share one 512 KB u l-panel (L2-hot).
    int wg = (int)blockIdx.x;
    wg = (wg & 7) * 64 + (wg >> 3);
    const int b    = wg >> 6;
    const int rest = wg & 63;
    const int h0 = (rest & 3) * 256;
    const int l0 = (rest >> 2) * 128;
    const int tid = (int)threadIdx.x;
    const int lane = tid & 63, wv = tid >> 6;

    // A staging: row srA = tid>>1 (0..255), k-half hfA = tid&1 (16 f32)
    const int srA = tid >> 1, hfA = tid & 1;
    const int pA  = srA >> 1;
    const int gA0i = (srA & 1) * 4 + 2 * hfA;
    const int wA0 = pA * 128 + ((gA0i)     ^ (pA & 7)) * 16;
    const int wA1 = pA * 128 + ((gA0i + 1) ^ (pA & 7)) * 16;
    const float* gA = Wf + (size_t)(h0 + srA) * DM + hfA * 16;

    // B staging: row srB = tid>>2 (0..127), quarter qf = tid&3 (8 f32)
    const int srB = tid >> 2, qf = tid & 3;
    const int pB  = srB >> 1;
    const int gBi = (srB & 1) * 4 + qf;
    const int wB0 = pB * 128 + (gBi ^ (pB & 7)) * 16;
    const float* gB = uf + ((size_t)b * L_SEQ + l0 + srB) * DM + qf * 8;

    const int wm = wv >> 1, wn = wv & 1;     // 4M x 2N
    const int lr = lane & 15, lk = lane >> 4;
    const int foff = (lr >> 1) * 128 + ((((lr & 1) << 2) + lk) ^ (lr >> 1)) * 16;

    f32x4 acc[4][4];
    #pragma unroll
    for (int m = 0; m < 4; ++m)
        #pragma unroll
        for (int n = 0; n < 4; ++n) acc[m][n] = (f32x4){0.f, 0.f, 0.f, 0.f};

    // prologue: stage tile 0
    {
        f32x4 a0 = *(const f32x4*)(gA),      a1 = *(const f32x4*)(gA + 4);
        f32x4 a2 = *(const f32x4*)(gA + 8),  a3 = *(const f32x4*)(gA + 12);
        f32x4 b0 = *(const f32x4*)(gB),      b1 = *(const f32x4*)(gB + 4);
        *(short8*)((char*)&As[0][0] + wA0) = pack8(a0, a1);
        *(short8*)((char*)&As[0][0] + wA1) = pack8(a2, a3);
        *(short8*)((char*)&Bs[0][0] + wB0) = pack8(b0, b1);
    }
    __syncthreads();

    #pragma unroll 1
    for (int t = 0; t < 32; ++t) {
        const int cur = t & 1;
        const char* Ab = (const char*)&As[cur][0];
        const char* Bb = (const char*)&Bs[cur][0];
        f32x4 a0, a1, a2, a3, b0, b1;
        if (t < 31) {   // issue next-tile loads early (T14 split)
            const int ko = (t + 1) * 32;
            a0 = *(const f32x4*)(gA + ko);     a1 = *(const f32x4*)(gA + ko + 4);
            a2 = *(const f32x4*)(gA + ko + 8); a3 = *(const f32x4*)(gA + ko + 12);
            b0 = *(const f32x4*)(gB + ko);     b1 = *(const f32x4*)(gB + ko + 4);
        }
        short8 af[4], bfr[4];
        #pragma unroll
        for (int nf = 0; nf < 4; ++nf)
            bfr[nf] = *(const short8*)(Bb + (wn * 64 + nf * 16) * 64 + foff);
        #pragma unroll
        for (int mf = 0; mf < 4; ++mf)
            af[mf] = *(const short8*)(Ab + (wm * 64 + mf * 16) * 64 + foff);
        __builtin_amdgcn_s_setprio(1);
        #pragma unroll
        for (int mf = 0; mf < 4; ++mf)
            #pragma unroll
            for (int nf = 0; nf < 4; ++nf)
                acc[mf][nf] = __builtin_amdgcn_mfma_f32_16x16x32_bf16(af[mf], bfr[nf], acc[mf][nf], 0, 0, 0);
        __builtin_amdgcn_s_setprio(0);
        __builtin_amdgcn_sched_barrier(0);   // keep cvt (and its vmcnt wait) after MFMAs
        if (t < 31) {
            char* An = (char*)&As[cur ^ 1][0];
            char* Bn = (char*)&Bs[cur ^ 1][0];
            *(short8*)(An + wA0) = pack8(a0, a1);
            *(short8*)(An + wA1) = pack8(a2, a3);
            *(short8*)(Bn + wB0) = pack8(b0, b1);
            __syncthreads();
        }
    }

    // epilogue: D row=(lane>>4)*4+reg (h), col=lane&15 (l)
    #pragma unroll
    for (int mf = 0; mf < 4; ++mf) {
        const int h = h0 + wm * 64 + mf * 16 + lk * 4;
        #pragma unroll
        for (int nf = 0; nf < 4; ++nf) {
            const int l = l0 + wn * 64 + nf * 16 + lr;
            #pragma unroll
            for (int r = 0; r < 4; ++r) {
                float v = acc[mf][nf][r] + bias[h + r];
                klin[((size_t)b * DM + h + r) * L_SEQ + l] = f2bf(v);
            }
        }
    }
}

// ---------------- expand: one block per (h, b-pair); 29.7KB LDS (unchanged) ----
__device__ inline void get_disc(const float* __restrict__ log_dt,
                                const float* __restrict__ lar,
                                const float* __restrict__ aim, int h, int n,
                                float& Are, float& Aim, float& lre, float& lim)
{
    float dtv = expf(log_dt[h]);
    Are = -expf(lar[h * 64 + n]);
    Aim = aim[h * 64 + n];
    lre = dtv * Are;
    lim = dtv * Aim;
}

__global__ __launch_bounds__(256, 5) void expand(
    const unsigned short* __restrict__ klin,
    const float* __restrict__ shift_B, const float* __restrict__ shift_C,
    const float* __restrict__ ssm_k_D, const float* __restrict__ log_dt,
    const float* __restrict__ log_A_real, const float* __restrict__ A_imag,
    const float* __restrict__ B_re, const float* __restrict__ B_im,
    float* __restrict__ out)
{
    __shared__ __align__(16) char sm[29696];
    constexpr int OKL = 0;
    constexpr int OKK = 8704;
    constexpr int OAF = 16896;
    constexpr int OPR = 20224;
    constexpr int OPI = 24320;
    constexpr int OF  = 28416;
    constexpr int OBS = 28672;
    constexpr int OCS = 28928;
    constexpr int OW32 = 29184;

    const int h  = blockIdx.x;
    const int bg = blockIdx.y;
    const int t = threadIdx.x;
    const int lane = t & 63, wv = t >> 6;

    if (t < 32) {
        int rl = t >> 4, reg = (t >> 3) & 1, idx = t & 7;
        *(f32x4*)&sm[OKL + rl * 4352 + reg * 4224 + idx * 16] = (f32x4){0.f, 0.f, 0.f, 0.f};
    }
    {
        const int rl = wv >> 1, hf = wv & 1;
        const int b = bg * 2 + rl;
        const char* krow = (const char*)(klin + ((size_t)b * DM + h) * L_SEQ);
        const int s = (2 * rl + 1 + (lane >> 3)) & 7;
        const int so = hf * 2048 + (lane >> 3) * 128 + ((lane ^ s) & 7) * 16;
        gload_lds16(krow + so,        &sm[OKL + rl * 4352 + 128 + hf * 2048]);
        gload_lds16(krow + so + 1024, &sm[OKL + rl * 4352 + 128 + hf * 2048 + 1024]);
    }
    if (t < 64) {
        ((float*)&sm[OBS])[t] = shift_B[h * 64 + t];
        ((float*)&sm[OCS])[t] = shift_C[h * 64 + t];
        float Are, Aim, lre, lim;
        get_disc(log_dt, log_A_real, A_imag, h, t, Are, Aim, lre, lim);
        float er = expf(32.f * lre);
        float sn, cs; sincosf(32.f * lim, &sn, &cs);
        ((float*)&sm[OW32])[t * 2]     = er * cs;
        ((float*)&sm[OW32])[t * 2 + 1] = er * sn;
    }
    {
        int n = t >> 2, s4 = t & 3;
        float Are, Aim, lre, lim;
        get_disc(log_dt, log_A_real, A_imag, h, n, Are, Aim, lre, lim);
        float erw = expf(lre), snw, csw;
        sincosf(lim, &snw, &csw);
        float wr = erw * csw, wi = erw * snw;
        float e0 = (float)(24 - 8 * s4);
        float mag = expf(e0 * lre);
        float sn0, cs0; sincosf(e0 * lim, &sn0, &cs0);
        float pr = mag * cs0, pi = mag * sn0;
        float vr[8], vi[8];
        vr[7] = pr; vi[7] = pi;
        #pragma unroll
        for (int k = 6; k >= 0; --k) {
            float nr = pr * wr - pi * wi;
            pi = fmaf(pr, wi, pi * wr);
            pr = nr;
            vr[k] = pr; vi[k] = pi;
        }
        short8 re8, im8;
        #pragma unroll
        for (int e = 0; e < 8; ++e) {
            re8[e] = (short)f2bf(vr[e]);
            im8[e] = (short)f2bf(vi[e]);
        }
        *(short8*)&sm[OPR + t * 16] = re8;
        *(short8*)&sm[OPI + t * 16] = im8;
    }
    __syncthreads();   // B1

    if (t < 64) {
        const float* Bp = (const float*)&sm[OBS];
        const float* Cp = (const float*)&sm[OCS];
        float f = (t == 0) ? ssm_k_D[h] : 0.f;
        #pragma unroll 8
        for (int j = 0; j < 64; ++j) {
            float cv = Cp[(j + t) & 63];
            f = fmaf((j + t < 64) ? cv : 0.f, Bp[j], f);
        }
        ((float*)&sm[OF])[t] = f;
    }
    __syncthreads();   // B2

    {
        int i = t >> 4, ks = t & 15;
        if (ks < 12) {
            const float* Fp = (const float*)&sm[OF];
            short8 row;
            #pragma unroll
            for (int e = 0; e < 8; ++e) {
                int k = ks * 8 + e;
                int m = 64 + i - k;
                float v = (m >= 0 && m < 64) ? Fp[m] : 0.f;
                row[e] = (short)f2bf(v);
            }
            *(short8*)&sm[OAF + i * 208 + ks * 16] = row;
        }
    }
    __syncthreads();   // B3

    {
        short8 afr[3];
        #pragma unroll
        for (int ks = 0; ks < 3; ++ks)
            afr[ks] = *(const short8*)&sm[OAF + (lane & 15) * 208 + ks * 64 + (lane >> 4) * 16];
        const int rl = wv >> 1;
        const int jbase = (wv & 1) * 4;
        #pragma unroll
        for (int jj = 0; jj < 4; ++jj) {
            const int jg = jbase + jj;
            f32x4 d = (f32x4){0.f, 0.f, 0.f, 0.f};
            #pragma unroll
            for (int ks = 0; ks < 3; ++ks) {
                int o = rl * 4352 + (jg * 256 + (lane & 15) * 16 + ks * 32 + (lane >> 4) * 8) * 2;
                o ^= ((o >> 7) & 7) << 4;     // SWL
                short8 bfrag = *(const short8*)&sm[OKL + o];
                d = __builtin_amdgcn_mfma_f32_16x16x32_bf16(afr[ks], bfrag, d, 0, 0, 0);
            }
            unsigned pk0 = ((unsigned)f2bf(d[0])) | (((unsigned)f2bf(d[1])) << 16);
            unsigned pk1 = ((unsigned)f2bf(d[2])) | (((unsigned)f2bf(d[3])) << 16);
            int o2 = rl * 4096 + jg * 512 + (lane & 15) * 32 + (lane >> 4) * 8;
            o2 ^= ((o2 >> 9) & 7) << 4;       // SWK
            *(u32x2*)&sm[OKK + o2] = (u32x2){pk0, pk1};
        }
    }
    __syncthreads();   // B4

    {
        const int mt = wv;
        short8 par = *(const short8*)&sm[OPR + (mt * 16 + (lane & 15)) * 64 + (lane >> 4) * 16];
        short8 pai = *(const short8*)&sm[OPI + (mt * 16 + (lane & 15)) * 64 + (lane >> 4) * 16];
        float w32r[4], w32i[4];
        #pragma unroll
        for (int rg = 0; rg < 4; ++rg) {
            int n = mt * 16 + (lane >> 4) * 4 + rg;
            float2 ww = *(const float2*)&sm[OW32 + n * 8];
            w32r[rg] = ww.x;
            w32i[rg] = ww.y;
        }
        f32x4 cr = (f32x4){0.f, 0.f, 0.f, 0.f};
        f32x4 ci_ = (f32x4){0.f, 0.f, 0.f, 0.f};
        const int colb = (lane & 15) >> 3;
        const int colr = lane & 7;
        #pragma unroll
        for (int g2 = 0; g2 < 8; ++g2) {
            int o = colb * 4096 + colr * 512 + g2 * 64 + (lane >> 4) * 16;
            o ^= ((o >> 9) & 7) << 4;         // SWK
            short8 kf = *(const short8*)&sm[OKK + o];
            f32x4 sre = __builtin_amdgcn_mfma_f32_16x16x32_bf16(par, kf, (f32x4){0.f,0.f,0.f,0.f}, 0, 0, 0);
            f32x4 sim = __builtin_amdgcn_mfma_f32_16x16x32_bf16(pai, kf, (f32x4){0.f,0.f,0.f,0.f}, 0, 0, 0);
            #pragma unroll
            for (int rg = 0; rg < 4; ++rg) {
                float wr = w32r[rg], wi = w32i[rg];
                float ncr = fmaf(cr[rg], wr, fmaf(-ci_[rg], wi, sre[rg]));
                float nci = fmaf(cr[rg], wi, fmaf(ci_[rg], wr, sim[rg]));
                cr[rg] = ncr;
                ci_[rg] = nci;
            }
        }
        __syncthreads();   // B5
        #pragma unroll
        for (int rg = 0; rg < 4; ++rg) {
            int n = mt * 16 + (lane >> 4) * 4 + rg;
            int c = lane & 15;
            ((float*)&sm[OKK])[n * 17 + c] = cr[rg];
            ((float*)&sm[OKK])[1088 + n * 17 + c] = ci_[rg];
        }
    }
    __syncthreads();   // B6

    if (t < 128) {
        const int n = t & 63, bl = t >> 6;
        const int b = bg * 2 + bl;
        float Are, Aim, lre, lim;
        get_disc(log_dt, log_A_real, A_imag, h, n, Are, Aim, lre, lim);
        float er = expf(lre), sn, cs;
        sincosf(lim, &sn, &cs);
        float wr = er * cs, wi = er * sn;
        float2 w32v = *(const float2*)&sm[OW32 + n * 8];
        float ar = w32v.x, ai = w32v.y;
        #pragma unroll
        for (int s = 0; s < 3; ++s) {
            float nr = ar * ar - ai * ai;
            ai = 2.f * ar * ai;
            ar = nr;
        }
        float den = Are * Are + Aim * Aim;
        float wm1r = wr - 1.f, wm1i = wi;
        float tr_ = (wm1r * Are + wm1i * Aim) / den;
        float ti_ = (wm1i * Are - wm1r * Aim) / den;
        float br = B_re[h * 64 + n], bi = B_im[h * 64 + n];
        float dBr = br * tr_ - bi * ti_;
        float dBi = br * ti_ + bi * tr_;
        const float* cre = (const float*)&sm[OKK] + n * 17 + bl * 8;
        const float* cim = (const float*)&sm[OKK] + 1088 + n * 17 + bl * 8;
        float sr = 0.f, si_ = 0.f;
        #pragma unroll
        for (int r = 0; r < 8; ++r) {
            float nsr = fmaf(ar, sr, fmaf(-ai, si_, cre[r]));
            float nsi = fmaf(ar, si_, fmaf(ai, sr, cim[r]));
            sr = nsr; si_ = nsi;
            out[(((size_t)b * NREC + r) * DM + h) * 64 + n] = dBr * sr - dBi * si_;
        }
    }
}

extern "C" void kernel_launch(void* const* d_in, const int* in_sizes, int n_in,
                              void* d_out, int out_size, void* d_ws, size_t ws_size,
                              hipStream_t stream)
{
    const float* u       = (const float*)d_in[0];
    const float* W       = (const float*)d_in[1];
    const float* bias    = (const float*)d_in[2];
    const float* shift_B = (const float*)d_in[3];
    const float* shift_C = (const float*)d_in[4];
    const float* ssm_k_D = (const float*)d_in[5];
    const float* log_dt  = (const float*)d_in[6];
    const float* log_Ar  = (const float*)d_in[7];
    const float* A_imag  = (const float*)d_in[8];
    const float* B_re    = (const float*)d_in[9];
    const float* B_im    = (const float*)d_in[10];
    float* out = (float*)d_out;

    unsigned short* klin = (unsigned short*)d_ws;   // 32 MB

    gemm_fused<<<dim3(512), 512, 0, stream>>>(W, u, bias, klin);

    expand<<<dim3(DM, 4), 256, 0, stream>>>(klin, shift_B, shift_C, ssm_k_D, log_dt,
                                            log_Ar, A_imag, B_re, B_im, out);
}

// Round 11
// 82.161 us; speedup vs baseline: 1.3418x; 1.1987x over previous
//
#include <hip/hip_runtime.h>
#include <cstddef>
#include <cstdint>

#define L_SEQ 2048
#define DM    1024
#define NREC  8

typedef __attribute__((ext_vector_type(8))) short short8;
typedef __attribute__((ext_vector_type(4))) float f32x4;
typedef __attribute__((ext_vector_type(2))) unsigned int u32x2;

__device__ inline unsigned short f2bf(float f) {
    unsigned u = __float_as_uint(f);
    unsigned r = (u + 0x7FFFu + ((u >> 16) & 1u)) >> 16;
    return (unsigned short)r;
}
__device__ inline void gload_lds16(const void* g, void* l) {
    __builtin_amdgcn_global_load_lds(
        (const __attribute__((address_space(1))) void*)g,
        (__attribute__((address_space(3))) void*)l, 16, 0, 0);
}
__device__ inline short8 pack8(f32x4 x, f32x4 y) {
    short8 c;
    c[0] = (short)f2bf(x[0]); c[1] = (short)f2bf(x[1]);
    c[2] = (short)f2bf(x[2]); c[3] = (short)f2bf(x[3]);
    c[4] = (short)f2bf(y[0]); c[5] = (short)f2bf(y[1]);
    c[6] = (short)f2bf(y[2]); c[7] = (short)f2bf(y[3]);
    return c;
}
__device__ inline void get_disc(const float* __restrict__ log_dt,
                                const float* __restrict__ lar,
                                const float* __restrict__ aim, int h, int n,
                                float& Are, float& Aim, float& lre, float& lim)
{
    float dtv = expf(log_dt[h]);
    Are = -expf(lar[h * 64 + n]);
    Aim = aim[h * 64 + n];
    lre = dtv * Are;
    lim = dtv * Aim;
}

// ---------------- tables: per-h constants, computed ONCE (was 4x in expand) ----
// 128 blocks x 512 thr; block handles h = 8*bid .. +7 (hs = t>>6, n = t&63).
// Writes: w32 (w^32, f32x2), dB (f32x2), P32 re/im (32 bf16/row, layout
// matching expand's frag read), Afir (16 x 104 bf16 Toeplitz of taps).
__global__ __launch_bounds__(512, 2) void tables(
    const float* __restrict__ shift_B, const float* __restrict__ shift_C,
    const float* __restrict__ ssm_k_D, const float* __restrict__ log_dt,
    const float* __restrict__ log_A_real, const float* __restrict__ A_imag,
    const float* __restrict__ B_re, const float* __restrict__ B_im,
    unsigned short* __restrict__ Pre_g, unsigned short* __restrict__ Pim_g,
    unsigned short* __restrict__ Afir_g, float* __restrict__ w32_g,
    float* __restrict__ dB_g)
{
    __shared__ float Fsh[8][64];
    const int t = (int)threadIdx.x;
    const int hs = t >> 6, n = t & 63;
    const int h = (int)blockIdx.x * 8 + hs;

    float Are, Aim, lre, lim;
    get_disc(log_dt, log_A_real, A_imag, h, n, Are, Aim, lre, lim);

    {   // w32 = w^32
        float er = expf(32.f * lre), sn, cs;
        sincosf(32.f * lim, &sn, &cs);
        ((float2*)w32_g)[h * 64 + n] = make_float2(er * cs, er * sn);
    }
    float wr, wi;
    {   // w and dB
        float er = expf(lre), sn, cs;
        sincosf(lim, &sn, &cs);
        wr = er * cs; wi = er * sn;
        float den = Are * Are + Aim * Aim;
        float wm1r = wr - 1.f, wm1i = wi;
        float tr_ = (wm1r * Are + wm1i * Aim) / den;
        float ti_ = (wm1i * Are - wm1r * Aim) / den;
        float br = B_re[h * 64 + n], bi = B_im[h * 64 + n];
        ((float2*)dB_g)[h * 64 + n] = make_float2(br * tr_ - bi * ti_, br * ti_ + bi * tr_);
    }
    {   // P32[n][j] = w^{31-j}, 4 segments of 8 (identical arithmetic to old expand)
        #pragma unroll
        for (int s4 = 0; s4 < 4; ++s4) {
            float e0 = (float)(24 - 8 * s4);
            float mag = expf(e0 * lre), sn0, cs0;
            sincosf(e0 * lim, &sn0, &cs0);
            float pr = mag * cs0, pi = mag * sn0;
            float vr[8], vi[8];
            vr[7] = pr; vi[7] = pi;
            #pragma unroll
            for (int k = 6; k >= 0; --k) {
                float nr = pr * wr - pi * wi;
                pi = fmaf(pr, wi, pi * wr);
                pr = nr;
                vr[k] = pr; vi[k] = pi;
            }
            short8 re8, im8;
            #pragma unroll
            for (int e = 0; e < 8; ++e) {
                re8[e] = (short)f2bf(vr[e]);
                im8[e] = (short)f2bf(vi[e]);
            }
            *(short8*)(Pre_g + (size_t)h * 2048 + n * 32 + s4 * 8) = re8;
            *(short8*)(Pim_g + (size_t)h * 2048 + n * 32 + s4 * 8) = im8;
        }
    }
    {   // taps F[m] = sum_j C[j+m] B[j] (+D at m=0)
        const float* Bp = shift_B + h * 64;
        const float* Cp = shift_C + h * 64;
        float f = (n == 0) ? ssm_k_D[h] : 0.f;
        for (int j = 0; j + n < 64; ++j) f = fmaf(Cp[j + n], Bp[j], f);
        Fsh[hs][n] = f;
    }
    __syncthreads();
    {   // Afir[i][k] = F[64+i-k]; 16 rows x 104 elems (only 12 short8 slots used)
        const float* Fp = Fsh[hs];
        const int i = n >> 2;
        for (int ks = (n & 3); ks < 12; ks += 4) {
            short8 row;
            #pragma unroll
            for (int e = 0; e < 8; ++e) {
                int k = ks * 8 + e;
                int m = 64 + i - k;
                row[e] = (short)f2bf((m >= 0 && m < 64) ? Fp[m] : 0.f);
            }
            *(short8*)(Afir_g + (size_t)h * 1664 + i * 104 + ks * 8) = row;
        }
    }
}

// ======== fused-cvt 256x256 GEMM (EXACT r8 kernel — proven stable, VGPR 104)
__global__ __launch_bounds__(512, 2) void gemm_fused(
    const float* __restrict__ Wf, const float* __restrict__ uf,
    const float* __restrict__ bias, unsigned short* __restrict__ klin)
{
    __shared__ unsigned short As[2][256 * 32];   // 2 x 16 KB
    __shared__ unsigned short Bs[2][256 * 32];   // 2 x 16 KB

    int wg = (int)blockIdx.x;
    wg = (wg & 7) * 32 + (wg >> 3);
    const int b  = wg >> 5;
    const int l0 = ((wg >> 2) & 7) * 256;
    const int h0 = (wg & 3) * 256;
    const int tid = (int)threadIdx.x;
    const int lane = tid & 63, wv = tid >> 6;

    const int sr0  = tid >> 2;        // 0..127
    const int slot = tid & 3;
    const int sr1  = sr0 + 128;
    const float* gA0 = Wf + (size_t)(h0 + sr0) * DM + slot * 8;
    const float* gA1 = Wf + (size_t)(h0 + sr1) * DM + slot * 8;
    const float* gB0 = uf + ((size_t)b * L_SEQ + l0 + sr0) * DM + slot * 8;
    const float* gB1 = uf + ((size_t)b * L_SEQ + l0 + sr1) * DM + slot * 8;
    const int w0off = (sr0 >> 1) * 128 + ((((sr0 & 1) << 2) + slot) ^ ((sr0 >> 1) & 7)) * 16;
    const int w1off = (sr1 >> 1) * 128 + ((((sr1 & 1) << 2) + slot) ^ ((sr1 >> 1) & 7)) * 16;

    const int wm = wv >> 2, wn = wv & 3;
    const int lr = lane & 15, lk = lane >> 4;
    const int foff = (lr >> 1) * 128 + ((((lr & 1) << 2) + lk) ^ (lr >> 1)) * 16;

    f32x4 acc[8][4];
    #pragma unroll
    for (int mf = 0; mf < 8; ++mf)
        #pragma unroll
        for (int nf = 0; nf < 4; ++nf) acc[mf][nf] = (f32x4){0.f, 0.f, 0.f, 0.f};

    {
        f32x4 a0 = *(const f32x4*)(gA0), a1 = *(const f32x4*)(gA0 + 4);
        f32x4 a2 = *(const f32x4*)(gA1), a3 = *(const f32x4*)(gA1 + 4);
        f32x4 b0 = *(const f32x4*)(gB0), b1 = *(const f32x4*)(gB0 + 4);
        f32x4 b2 = *(const f32x4*)(gB1), b3 = *(const f32x4*)(gB1 + 4);
        *(short8*)((char*)&As[0][0] + w0off) = pack8(a0, a1);
        *(short8*)((char*)&As[0][0] + w1off) = pack8(a2, a3);
        *(short8*)((char*)&Bs[0][0] + w0off) = pack8(b0, b1);
        *(short8*)((char*)&Bs[0][0] + w1off) = pack8(b2, b3);
    }
    __syncthreads();

    #pragma unroll 1
    for (int t = 0; t < 32; ++t) {
        const int cur = t & 1;
        const char* Ab = (const char*)&As[cur][0];
        const char* Bb = (const char*)&Bs[cur][0];
        f32x4 a0, a1, a2, a3, b0, b1, b2, b3;
        if (t < 31) {
            const int ko = (t + 1) * 32;
            a0 = *(const f32x4*)(gA0 + ko); a1 = *(const f32x4*)(gA0 + ko + 4);
            a2 = *(const f32x4*)(gA1 + ko); a3 = *(const f32x4*)(gA1 + ko + 4);
            b0 = *(const f32x4*)(gB0 + ko); b1 = *(const f32x4*)(gB0 + ko + 4);
            b2 = *(const f32x4*)(gB1 + ko); b3 = *(const f32x4*)(gB1 + ko + 4);
        }
        short8 af[4], bfr[4];
        #pragma unroll
        for (int nf = 0; nf < 4; ++nf)
            bfr[nf] = *(const short8*)(Bb + (wn * 64 + nf * 16) * 64 + foff);
        #pragma unroll
        for (int mf = 0; mf < 4; ++mf)
            af[mf] = *(const short8*)(Ab + (wm * 128 + mf * 16) * 64 + foff);
        __builtin_amdgcn_s_setprio(1);
        #pragma unroll
        for (int mf = 0; mf < 4; ++mf)
            #pragma unroll
            for (int nf = 0; nf < 4; ++nf)
                acc[mf][nf] = __builtin_amdgcn_mfma_f32_16x16x32_bf16(af[mf], bfr[nf], acc[mf][nf], 0, 0, 0);
        __builtin_amdgcn_s_setprio(0);
        #pragma unroll
        for (int mf = 0; mf < 4; ++mf)
            af[mf] = *(const short8*)(Ab + (wm * 128 + (mf + 4) * 16) * 64 + foff);
        __builtin_amdgcn_s_setprio(1);
        #pragma unroll
        for (int mf = 0; mf < 4; ++mf)
            #pragma unroll
            for (int nf = 0; nf < 4; ++nf)
                acc[mf + 4][nf] = __builtin_amdgcn_mfma_f32_16x16x32_bf16(af[mf], bfr[nf], acc[mf + 4][nf], 0, 0, 0);
        __builtin_amdgcn_s_setprio(0);
        __builtin_amdgcn_sched_barrier(0);
        if (t < 31) {
            char* An = (char*)&As[cur ^ 1][0];
            char* Bn = (char*)&Bs[cur ^ 1][0];
            *(short8*)(An + w0off) = pack8(a0, a1);
            *(short8*)(An + w1off) = pack8(a2, a3);
            *(short8*)(Bn + w0off) = pack8(b0, b1);
            *(short8*)(Bn + w1off) = pack8(b2, b3);
            __syncthreads();
        }
    }

    #pragma unroll
    for (int mf = 0; mf < 8; ++mf) {
        const int h = h0 + wm * 128 + mf * 16 + lk * 4;
        #pragma unroll
        for (int nf = 0; nf < 4; ++nf) {
            const int l = l0 + wn * 64 + nf * 16 + lr;
            #pragma unroll
            for (int r = 0; r < 4; ++r) {
                float v = acc[mf][nf][r] + bias[h + r];
                klin[((size_t)b * DM + h + r) * L_SEQ + l] = f2bf(v);
            }
        }
    }
}

// ---------------- expand: stripped — tables from global, 3 barriers, 16.9KB LDS ----
__global__ __launch_bounds__(256, 5) void expand(
    const unsigned short* __restrict__ klin,
    const unsigned short* __restrict__ Pre_g, const unsigned short* __restrict__ Pim_g,
    const unsigned short* __restrict__ Afir_g, const float* __restrict__ w32_g,
    const float* __restrict__ dB_g, float* __restrict__ out)
{
    __shared__ __align__(16) char sm[16896];
    constexpr int OKL = 0;      // 2 x 4352 (kl; ctb overlays after FIR: re 4352 + im 4352)
    constexpr int OKK = 8704;   // 2 x 4096 (kk, SWK)

    const int h  = (int)blockIdx.x;
    const int bg = (int)blockIdx.y;
    const int t = (int)threadIdx.x;
    const int lane = t & 63, wv = t >> 6;

    if (t < 32) {   // zero prefix/tail of kl
        int rl = t >> 4, reg = (t >> 3) & 1, idx = t & 7;
        *(f32x4*)&sm[OKL + rl * 4352 + reg * 4224 + idx * 16] = (f32x4){0.f, 0.f, 0.f, 0.f};
    }
    {   // stage kl rows via swizzled-source gload_lds
        const int rl = wv >> 1, hf = wv & 1;
        const int b = bg * 2 + rl;
        const char* krow = (const char*)(klin + ((size_t)b * DM + h) * L_SEQ);
        const int s = (2 * rl + 1 + (lane >> 3)) & 7;
        const int so = hf * 2048 + (lane >> 3) * 128 + ((lane ^ s) & 7) * 16;
        gload_lds16(krow + so,        &sm[OKL + rl * 4352 + 128 + hf * 2048]);
        gload_lds16(krow + so + 1024, &sm[OKL + rl * 4352 + 128 + hf * 2048 + 1024]);
    }
    // early table loads (no dependency on staging; latency hides under barrier)
    short8 afr[3];
    #pragma unroll
    for (int ks = 0; ks < 3; ++ks)
        afr[ks] = *(const short8*)(Afir_g + (size_t)h * 1664 + (lane & 15) * 104 + ks * 32 + (lane >> 4) * 8);
    const int mt = wv;
    short8 par = *(const short8*)(Pre_g + (size_t)h * 2048 + (mt * 16 + (lane & 15)) * 32 + (lane >> 4) * 8);
    short8 pai = *(const short8*)(Pim_g + (size_t)h * 2048 + (mt * 16 + (lane & 15)) * 32 + (lane >> 4) * 8);
    float w32r[4], w32i[4];
    #pragma unroll
    for (int rg = 0; rg < 4; ++rg) {
        int n = mt * 16 + (lane >> 4) * 4 + rg;
        float2 ww = ((const float2*)w32_g)[h * 64 + n];
        w32r[rg] = ww.x; w32i[rg] = ww.y;
    }
    __syncthreads();   // B1: kl staged (drains vmcnt/lgkmcnt)

    {   // FIR via MFMA: wave wv -> row rl=wv>>1, jg in [4*(wv&1), +4)
        const int rl = wv >> 1;
        const int jbase = (wv & 1) * 4;
        #pragma unroll
        for (int jj = 0; jj < 4; ++jj) {
            const int jg = jbase + jj;
            f32x4 d = (f32x4){0.f, 0.f, 0.f, 0.f};
            #pragma unroll
            for (int ks = 0; ks < 3; ++ks) {
                int o = rl * 4352 + (jg * 256 + (lane & 15) * 16 + ks * 32 + (lane >> 4) * 8) * 2;
                o ^= ((o >> 7) & 7) << 4;     // SWL
                short8 bfrag = *(const short8*)&sm[OKL + o];
                d = __builtin_amdgcn_mfma_f32_16x16x32_bf16(afr[ks], bfrag, d, 0, 0, 0);
            }
            unsigned pk0 = ((unsigned)f2bf(d[0])) | (((unsigned)f2bf(d[1])) << 16);
            unsigned pk1 = ((unsigned)f2bf(d[2])) | (((unsigned)f2bf(d[3])) << 16);
            int o2 = rl * 4096 + jg * 512 + (lane & 15) * 32 + (lane >> 4) * 8;
            o2 ^= ((o2 >> 9) & 7) << 4;       // SWK
            *(u32x2*)&sm[OKK + o2] = (u32x2){pk0, pk1};
        }
    }
    __syncthreads();   // B4: kk ready, kl dead

    {   // contrib via MFMA + w32-Horner; ctb overlays kl region
        f32x4 cr = (f32x4){0.f, 0.f, 0.f, 0.f};
        f32x4 ci_ = (f32x4){0.f, 0.f, 0.f, 0.f};
        const int colb = (lane & 15) >> 3;
        const int colr = lane & 7;
        #pragma unroll
        for (int g2 = 0; g2 < 8; ++g2) {
            int o = colb * 4096 + colr * 512 + g2 * 64 + (lane >> 4) * 16;
            o ^= ((o >> 9) & 7) << 4;         // SWK
            short8 kf = *(const short8*)&sm[OKK + o];
            f32x4 sre = __builtin_amdgcn_mfma_f32_16x16x32_bf16(par, kf, (f32x4){0.f,0.f,0.f,0.f}, 0, 0, 0);
            f32x4 sim = __builtin_amdgcn_mfma_f32_16x16x32_bf16(pai, kf, (f32x4){0.f,0.f,0.f,0.f}, 0, 0, 0);
            #pragma unroll
            for (int rg = 0; rg < 4; ++rg) {
                float wr = w32r[rg], wi = w32i[rg];
                float ncr = fmaf(cr[rg], wr, fmaf(-ci_[rg], wi, sre[rg]));
                float nci = fmaf(cr[rg], wi, fmaf(ci_[rg], wr, sim[rg]));
                cr[rg] = ncr;
                ci_[rg] = nci;
            }
        }
        #pragma unroll
        for (int rg = 0; rg < 4; ++rg) {
            int n = mt * 16 + (lane >> 4) * 4 + rg;
            int c = lane & 15;
            ((float*)&sm[OKL])[n * 17 + c] = cr[rg];
            ((float*)&sm[OKL + 4352])[n * 17 + c] = ci_[rg];
        }
    }
    __syncthreads();   // B6: ctb ready

    if (t < 128) {   // scan over 8 chunks + dB readout
        const int n = t & 63, bl = t >> 6;
        const int b = bg * 2 + bl;
        float2 w32v = ((const float2*)w32_g)[h * 64 + n];
        float ar = w32v.x, ai = w32v.y;      // -> w^256 by 3 squarings
        #pragma unroll
        for (int s = 0; s < 3; ++s) {
            float nr = ar * ar - ai * ai;
            ai = 2.f * ar * ai;
            ar = nr;
        }
        float2 dBv = ((const float2*)dB_g)[h * 64 + n];
        const float* cre = (const float*)&sm[OKL] + n * 17 + bl * 8;
        const float* cim = (const float*)&sm[OKL + 4352] + n * 17 + bl * 8;
        float sr = 0.f, si_ = 0.f;
        #pragma unroll
        for (int r = 0; r < 8; ++r) {
            float nsr = fmaf(ar, sr, fmaf(-ai, si_, cre[r]));
            float nsi = fmaf(ar, si_, fmaf(ai, sr, cim[r]));
            sr = nsr; si_ = nsi;
            out[(((size_t)b * NREC + r) * DM + h) * 64 + n] = dBv.x * sr - dBv.y * si_;
        }
    }
}

extern "C" void kernel_launch(void* const* d_in, const int* in_sizes, int n_in,
                              void* d_out, int out_size, void* d_ws, size_t ws_size,
                              hipStream_t stream)
{
    const float* u       = (const float*)d_in[0];
    const float* W       = (const float*)d_in[1];
    const float* bias    = (const float*)d_in[2];
    const float* shift_B = (const float*)d_in[3];
    const float* shift_C = (const float*)d_in[4];
    const float* ssm_k_D = (const float*)d_in[5];
    const float* log_dt  = (const float*)d_in[6];
    const float* log_Ar  = (const float*)d_in[7];
    const float* A_imag  = (const float*)d_in[8];
    const float* B_re    = (const float*)d_in[9];
    const float* B_im    = (const float*)d_in[10];
    float* out = (float*)d_out;

    // workspace layout (bytes): klin 32M | Pre 4M | Pim 4M | Afir 3.25M | w32 .5M | dB .5M
    unsigned short* klin  = (unsigned short*)d_ws;
    unsigned short* Pre_g = klin + (size_t)8 * L_SEQ * DM;           // +32 MB
    unsigned short* Pim_g = Pre_g + (size_t)DM * 2048;               // +4 MB
    unsigned short* Afir_g = Pim_g + (size_t)DM * 2048;              // +4 MB
    float* w32_g = (float*)(Afir_g + (size_t)DM * 1664);             // +3.25 MB
    float* dB_g  = w32_g + (size_t)DM * 128;                         // +0.5 MB

    tables<<<dim3(128), 512, 0, stream>>>(shift_B, shift_C, ssm_k_D, log_dt,
                                          log_Ar, A_imag, B_re, B_im,
                                          Pre_g, Pim_g, Afir_g, w32_g, dB_g);

    gemm_fused<<<dim3(256), 512, 0, stream>>>(W, u, bias, klin);

    expand<<<dim3(DM, 4), 256, 0, stream>>>(klin, Pre_g, Pim_g, Afir_g, w32_g,
                                            dB_g, out);
}

// Round 12
// 74.188 us; speedup vs baseline: 1.4859x; 1.1075x over previous
//
#include <hip/hip_runtime.h>
#include <hip/hip_bf16.h>
#include <cstddef>
#include <cstdint>

#define L_SEQ 2048
#define DM    1024
#define NREC  8

typedef __attribute__((ext_vector_type(8))) short short8;
typedef __attribute__((ext_vector_type(4))) float f32x4;
typedef __attribute__((ext_vector_type(2))) unsigned int u32x2;

// native conversion: compiler fuses adjacent casts into v_cvt_pk_bf16_f32
// (RNE, bit-identical to the old manual rounding) — the old bit-twiddle was
// ~5 VALU ops/elem and blocked the fusion.
__device__ inline unsigned short f2bf(float f) {
    __hip_bfloat16 h = __float2bfloat16(f);
    return __builtin_bit_cast(unsigned short, h);
}
__device__ inline void gload_lds16(const void* g, void* l) {
    __builtin_amdgcn_global_load_lds(
        (const __attribute__((address_space(1))) void*)g,
        (__attribute__((address_space(3))) void*)l, 16, 0, 0);
}
__device__ inline short8 pack8(f32x4 x, f32x4 y) {
    short8 c;
    c[0] = (short)f2bf(x[0]); c[1] = (short)f2bf(x[1]);
    c[2] = (short)f2bf(x[2]); c[3] = (short)f2bf(x[3]);
    c[4] = (short)f2bf(y[0]); c[5] = (short)f2bf(y[1]);
    c[6] = (short)f2bf(y[2]); c[7] = (short)f2bf(y[3]);
    return c;
}

// ======== fused-cvt 256x256 GEMM (r8 structure — proven stable, VGPR 104) ====
// klin[b][h][l] = W[h][:].u[b][l][:] + bias.  8 waves (2M x 4N), BK=32,
// 2-deep LDS dbuf (64 KB), reg-staged T14: issue next tile's 8 f32x4 at tile
// top, 2 MFMA clusters (setprio), then cvt+swizzled ds_write late.
// LDS pair-granule swizzle (0-conflict, r6+): pair p=row>>1 holds 8 granules
// (128B); logical g=(row&1)*4+slot; phys = g ^ (p&7).
__global__ __launch_bounds__(512, 2) void gemm_fused(
    const float* __restrict__ Wf, const float* __restrict__ uf,
    const float* __restrict__ bias, unsigned short* __restrict__ klin)
{
    __shared__ unsigned short As[2][256 * 32];   // 2 x 16 KB
    __shared__ unsigned short Bs[2][256 * 32];   // 2 x 16 KB

    // XCD-contiguous: XCD x gets wg in [32x,32x+32) = one whole batch.
    int wg = (int)blockIdx.x;
    wg = (wg & 7) * 32 + (wg >> 3);
    const int b  = wg >> 5;
    const int l0 = ((wg >> 2) & 7) * 256;
    const int h0 = (wg & 3) * 256;
    const int tid = (int)threadIdx.x;
    const int lane = tid & 63, wv = tid >> 6;

    const int sr0  = tid >> 2;        // 0..127
    const int slot = tid & 3;
    const int sr1  = sr0 + 128;
    const float* gA0 = Wf + (size_t)(h0 + sr0) * DM + slot * 8;
    const float* gA1 = Wf + (size_t)(h0 + sr1) * DM + slot * 8;
    const float* gB0 = uf + ((size_t)b * L_SEQ + l0 + sr0) * DM + slot * 8;
    const float* gB1 = uf + ((size_t)b * L_SEQ + l0 + sr1) * DM + slot * 8;
    const int w0off = (sr0 >> 1) * 128 + ((((sr0 & 1) << 2) + slot) ^ ((sr0 >> 1) & 7)) * 16;
    const int w1off = (sr1 >> 1) * 128 + ((((sr1 & 1) << 2) + slot) ^ ((sr1 >> 1) & 7)) * 16;

    const int wm = wv >> 2, wn = wv & 3;
    const int lr = lane & 15, lk = lane >> 4;
    const int foff = (lr >> 1) * 128 + ((((lr & 1) << 2) + lk) ^ (lr >> 1)) * 16;

    f32x4 acc[8][4];
    #pragma unroll
    for (int mf = 0; mf < 8; ++mf)
        #pragma unroll
        for (int nf = 0; nf < 4; ++nf) acc[mf][nf] = (f32x4){0.f, 0.f, 0.f, 0.f};

    {   // prologue: stage tile 0
        f32x4 a0 = *(const f32x4*)(gA0), a1 = *(const f32x4*)(gA0 + 4);
        f32x4 a2 = *(const f32x4*)(gA1), a3 = *(const f32x4*)(gA1 + 4);
        f32x4 b0 = *(const f32x4*)(gB0), b1 = *(const f32x4*)(gB0 + 4);
        f32x4 b2 = *(const f32x4*)(gB1), b3 = *(const f32x4*)(gB1 + 4);
        *(short8*)((char*)&As[0][0] + w0off) = pack8(a0, a1);
        *(short8*)((char*)&As[0][0] + w1off) = pack8(a2, a3);
        *(short8*)((char*)&Bs[0][0] + w0off) = pack8(b0, b1);
        *(short8*)((char*)&Bs[0][0] + w1off) = pack8(b2, b3);
    }
    __syncthreads();

    #pragma unroll 1
    for (int t = 0; t < 32; ++t) {
        const int cur = t & 1;
        const char* Ab = (const char*)&As[cur][0];
        const char* Bb = (const char*)&Bs[cur][0];
        f32x4 a0, a1, a2, a3, b0, b1, b2, b3;
        if (t < 31) {   // issue next-tile loads early (T14 split)
            const int ko = (t + 1) * 32;
            a0 = *(const f32x4*)(gA0 + ko); a1 = *(const f32x4*)(gA0 + ko + 4);
            a2 = *(const f32x4*)(gA1 + ko); a3 = *(const f32x4*)(gA1 + ko + 4);
            b0 = *(const f32x4*)(gB0 + ko); b1 = *(const f32x4*)(gB0 + ko + 4);
            b2 = *(const f32x4*)(gB1 + ko); b3 = *(const f32x4*)(gB1 + ko + 4);
        }
        short8 af[4], bfr[4];
        // ---- phase 0: B frags + A mf0-3, 16 MFMA ----
        #pragma unroll
        for (int nf = 0; nf < 4; ++nf)
            bfr[nf] = *(const short8*)(Bb + (wn * 64 + nf * 16) * 64 + foff);
        #pragma unroll
        for (int mf = 0; mf < 4; ++mf)
            af[mf] = *(const short8*)(Ab + (wm * 128 + mf * 16) * 64 + foff);
        __builtin_amdgcn_s_setprio(1);
        #pragma unroll
        for (int mf = 0; mf < 4; ++mf)
            #pragma unroll
            for (int nf = 0; nf < 4; ++nf)
                acc[mf][nf] = __builtin_amdgcn_mfma_f32_16x16x32_bf16(af[mf], bfr[nf], acc[mf][nf], 0, 0, 0);
        __builtin_amdgcn_s_setprio(0);
        // ---- phase 1: A mf4-7 (reuse B frags), 16 MFMA ----
        #pragma unroll
        for (int mf = 0; mf < 4; ++mf)
            af[mf] = *(const short8*)(Ab + (wm * 128 + (mf + 4) * 16) * 64 + foff);
        __builtin_amdgcn_s_setprio(1);
        #pragma unroll
        for (int mf = 0; mf < 4; ++mf)
            #pragma unroll
            for (int nf = 0; nf < 4; ++nf)
                acc[mf + 4][nf] = __builtin_amdgcn_mfma_f32_16x16x32_bf16(af[mf], bfr[nf], acc[mf + 4][nf], 0, 0, 0);
        __builtin_amdgcn_s_setprio(0);
        __builtin_amdgcn_sched_barrier(0);   // keep cvt (and its vmcnt wait) after MFMAs
        // ---- write-late: cvt + swizzled ds_write into the other buffer ----
        if (t < 31) {
            char* An = (char*)&As[cur ^ 1][0];
            char* Bn = (char*)&Bs[cur ^ 1][0];
            *(short8*)(An + w0off) = pack8(a0, a1);
            *(short8*)(An + w1off) = pack8(a2, a3);
            *(short8*)(Bn + w0off) = pack8(b0, b1);
            *(short8*)(Bn + w1off) = pack8(b2, b3);
            __syncthreads();
        }
    }

    // epilogue: D row=(lane>>4)*4+reg (h), col=lane&15 (l)
    #pragma unroll
    for (int mf = 0; mf < 8; ++mf) {
        const int h = h0 + wm * 128 + mf * 16 + lk * 4;
        #pragma unroll
        for (int nf = 0; nf < 4; ++nf) {
            const int l = l0 + wn * 64 + nf * 16 + lr;
            #pragma unroll
            for (int r = 0; r < 4; ++r) {
                float v = acc[mf][nf][r] + bias[h + r];
                klin[((size_t)b * DM + h + r) * L_SEQ + l] = f2bf(v);
            }
        }
    }
}

// ---------------- expand: one block per (h, b-pair); 29.7KB LDS (r8 version) ----
__device__ inline void get_disc(const float* __restrict__ log_dt,
                                const float* __restrict__ lar,
                                const float* __restrict__ aim, int h, int n,
                                float& Are, float& Aim, float& lre, float& lim)
{
    float dtv = expf(log_dt[h]);
    Are = -expf(lar[h * 64 + n]);
    Aim = aim[h * 64 + n];
    lre = dtv * Are;
    lim = dtv * Aim;
}

__global__ __launch_bounds__(256, 5) void expand(
    const unsigned short* __restrict__ klin,
    const float* __restrict__ shift_B, const float* __restrict__ shift_C,
    const float* __restrict__ ssm_k_D, const float* __restrict__ log_dt,
    const float* __restrict__ log_A_real, const float* __restrict__ A_imag,
    const float* __restrict__ B_re, const float* __restrict__ B_im,
    float* __restrict__ out)
{
    __shared__ __align__(16) char sm[29696];
    constexpr int OKL = 0;
    constexpr int OKK = 8704;
    constexpr int OAF = 16896;
    constexpr int OPR = 20224;
    constexpr int OPI = 24320;
    constexpr int OF  = 28416;
    constexpr int OBS = 28672;
    constexpr int OCS = 28928;
    constexpr int OW32 = 29184;

    const int h  = blockIdx.x;
    const int bg = blockIdx.y;
    const int t = threadIdx.x;
    const int lane = t & 63, wv = t >> 6;

    if (t < 32) {
        int rl = t >> 4, reg = (t >> 3) & 1, idx = t & 7;
        *(f32x4*)&sm[OKL + rl * 4352 + reg * 4224 + idx * 16] = (f32x4){0.f, 0.f, 0.f, 0.f};
    }
    {
        const int rl = wv >> 1, hf = wv & 1;
        const int b = bg * 2 + rl;
        const char* krow = (const char*)(klin + ((size_t)b * DM + h) * L_SEQ);
        const int s = (2 * rl + 1 + (lane >> 3)) & 7;
        const int so = hf * 2048 + (lane >> 3) * 128 + ((lane ^ s) & 7) * 16;
        gload_lds16(krow + so,        &sm[OKL + rl * 4352 + 128 + hf * 2048]);
        gload_lds16(krow + so + 1024, &sm[OKL + rl * 4352 + 128 + hf * 2048 + 1024]);
    }
    if (t < 64) {
        ((float*)&sm[OBS])[t] = shift_B[h * 64 + t];
        ((float*)&sm[OCS])[t] = shift_C[h * 64 + t];
        float Are, Aim, lre, lim;
        get_disc(log_dt, log_A_real, A_imag, h, t, Are, Aim, lre, lim);
        float er = expf(32.f * lre);
        float sn, cs; sincosf(32.f * lim, &sn, &cs);
        ((float*)&sm[OW32])[t * 2]     = er * cs;
        ((float*)&sm[OW32])[t * 2 + 1] = er * sn;
    }
    {
        int n = t >> 2, s4 = t & 3;
        float Are, Aim, lre, lim;
        get_disc(log_dt, log_A_real, A_imag, h, n, Are, Aim, lre, lim);
        float erw = expf(lre), snw, csw;
        sincosf(lim, &snw, &csw);
        float wr = erw * csw, wi = erw * snw;
        float e0 = (float)(24 - 8 * s4);
        float mag = expf(e0 * lre);
        float sn0, cs0; sincosf(e0 * lim, &sn0, &cs0);
        float pr = mag * cs0, pi = mag * sn0;
        float vr[8], vi[8];
        vr[7] = pr; vi[7] = pi;
        #pragma unroll
        for (int k = 6; k >= 0; --k) {
            float nr = pr * wr - pi * wi;
            pi = fmaf(pr, wi, pi * wr);
            pr = nr;
            vr[k] = pr; vi[k] = pi;
        }
        short8 re8, im8;
        #pragma unroll
        for (int e = 0; e < 8; ++e) {
            re8[e] = (short)f2bf(vr[e]);
            im8[e] = (short)f2bf(vi[e]);
        }
        *(short8*)&sm[OPR + t * 16] = re8;
        *(short8*)&sm[OPI + t * 16] = im8;
    }
    __syncthreads();   // B1

    if (t < 64) {
        const float* Bp = (const float*)&sm[OBS];
        const float* Cp = (const float*)&sm[OCS];
        float f = (t == 0) ? ssm_k_D[h] : 0.f;
        #pragma unroll 8
        for (int j = 0; j < 64; ++j) {
            float cv = Cp[(j + t) & 63];
            f = fmaf((j + t < 64) ? cv : 0.f, Bp[j], f);
        }
        ((float*)&sm[OF])[t] = f;
    }
    __syncthreads();   // B2

    {
        int i = t >> 4, ks = t & 15;
        if (ks < 12) {
            const float* Fp = (const float*)&sm[OF];
            short8 row;
            #pragma unroll
            for (int e = 0; e < 8; ++e) {
                int k = ks * 8 + e;
                int m = 64 + i - k;
                float v = (m >= 0 && m < 64) ? Fp[m] : 0.f;
                row[e] = (short)f2bf(v);
            }
            *(short8*)&sm[OAF + i * 208 + ks * 16] = row;
        }
    }
    __syncthreads();   // B3

    {
        short8 afr[3];
        #pragma unroll
        for (int ks = 0; ks < 3; ++ks)
            afr[ks] = *(const short8*)&sm[OAF + (lane & 15) * 208 + ks * 64 + (lane >> 4) * 16];
        const int rl = wv >> 1;
        const int jbase = (wv & 1) * 4;
        #pragma unroll
        for (int jj = 0; jj < 4; ++jj) {
            const int jg = jbase + jj;
            f32x4 d = (f32x4){0.f, 0.f, 0.f, 0.f};
            #pragma unroll
            for (int ks = 0; ks < 3; ++ks) {
                int o = rl * 4352 + (jg * 256 + (lane & 15) * 16 + ks * 32 + (lane >> 4) * 8) * 2;
                o ^= ((o >> 7) & 7) << 4;     // SWL
                short8 bfrag = *(const short8*)&sm[OKL + o];
                d = __builtin_amdgcn_mfma_f32_16x16x32_bf16(afr[ks], bfrag, d, 0, 0, 0);
            }
            unsigned pk0 = ((unsigned)f2bf(d[0])) | (((unsigned)f2bf(d[1])) << 16);
            unsigned pk1 = ((unsigned)f2bf(d[2])) | (((unsigned)f2bf(d[3])) << 16);
            int o2 = rl * 4096 + jg * 512 + (lane & 15) * 32 + (lane >> 4) * 8;
            o2 ^= ((o2 >> 9) & 7) << 4;       // SWK
            *(u32x2*)&sm[OKK + o2] = (u32x2){pk0, pk1};
        }
    }
    __syncthreads();   // B4

    {
        const int mt = wv;
        short8 par = *(const short8*)&sm[OPR + (mt * 16 + (lane & 15)) * 64 + (lane >> 4) * 16];
        short8 pai = *(const short8*)&sm[OPI + (mt * 16 + (lane & 15)) * 64 + (lane >> 4) * 16];
        float w32r[4], w32i[4];
        #pragma unroll
        for (int rg = 0; rg < 4; ++rg) {
            int n = mt * 16 + (lane >> 4) * 4 + rg;
            float2 ww = *(const float2*)&sm[OW32 + n * 8];
            w32r[rg] = ww.x;
            w32i[rg] = ww.y;
        }
        f32x4 cr = (f32x4){0.f, 0.f, 0.f, 0.f};
        f32x4 ci_ = (f32x4){0.f, 0.f, 0.f, 0.f};
        const int colb = (lane & 15) >> 3;
        const int colr = lane & 7;
        #pragma unroll
        for (int g2 = 0; g2 < 8; ++g2) {
            int o = colb * 4096 + colr * 512 + g2 * 64 + (lane >> 4) * 16;
            o ^= ((o >> 9) & 7) << 4;         // SWK
            short8 kf = *(const short8*)&sm[OKK + o];
            f32x4 sre = __builtin_amdgcn_mfma_f32_16x16x32_bf16(par, kf, (f32x4){0.f,0.f,0.f,0.f}, 0, 0, 0);
            f32x4 sim = __builtin_amdgcn_mfma_f32_16x16x32_bf16(pai, kf, (f32x4){0.f,0.f,0.f,0.f}, 0, 0, 0);
            #pragma unroll
            for (int rg = 0; rg < 4; ++rg) {
                float wr = w32r[rg], wi = w32i[rg];
                float ncr = fmaf(cr[rg], wr, fmaf(-ci_[rg], wi, sre[rg]));
                float nci = fmaf(cr[rg], wi, fmaf(ci_[rg], wr, sim[rg]));
                cr[rg] = ncr;
                ci_[rg] = nci;
            }
        }
        __syncthreads();   // B5
        #pragma unroll
        for (int rg = 0; rg < 4; ++rg) {
            int n = mt * 16 + (lane >> 4) * 4 + rg;
            int c = lane & 15;
            ((float*)&sm[OKK])[n * 17 + c] = cr[rg];
            ((float*)&sm[OKK])[1088 + n * 17 + c] = ci_[rg];
        }
    }
    __syncthreads();   // B6

    if (t < 128) {
        const int n = t & 63, bl = t >> 6;
        const int b = bg * 2 + bl;
        float Are, Aim, lre, lim;
        get_disc(log_dt, log_A_real, A_imag, h, n, Are, Aim, lre, lim);
        float er = expf(lre), sn, cs;
        sincosf(lim, &sn, &cs);
        float wr = er * cs, wi = er * sn;
        float2 w32v = *(const float2*)&sm[OW32 + n * 8];
        float ar = w32v.x, ai = w32v.y;
        #pragma unroll
        for (int s = 0; s < 3; ++s) {
            float nr = ar * ar - ai * ai;
            ai = 2.f * ar * ai;
            ar = nr;
        }
        float den = Are * Are + Aim * Aim;
        float wm1r = wr - 1.f, wm1i = wi;
        float tr_ = (wm1r * Are + wm1i * Aim) / den;
        float ti_ = (wm1i * Are - wm1r * Aim) / den;
        float br = B_re[h * 64 + n], bi = B_im[h * 64 + n];
        float dBr = br * tr_ - bi * ti_;
        float dBi = br * ti_ + bi * tr_;
        const float* cre = (const float*)&sm[OKK] + n * 17 + bl * 8;
        const float* cim = (const float*)&sm[OKK] + 1088 + n * 17 + bl * 8;
        float sr = 0.f, si_ = 0.f;
        #pragma unroll
        for (int r = 0; r < 8; ++r) {
            float nsr = fmaf(ar, sr, fmaf(-ai, si_, cre[r]));
            float nsi = fmaf(ar, si_, fmaf(ai, sr, cim[r]));
            sr = nsr; si_ = nsi;
            out[(((size_t)b * NREC + r) * DM + h) * 64 + n] = dBr * sr - dBi * si_;
        }
    }
}

extern "C" void kernel_launch(void* const* d_in, const int* in_sizes, int n_in,
                              void* d_out, int out_size, void* d_ws, size_t ws_size,
                              hipStream_t stream)
{
    const float* u       = (const float*)d_in[0];
    const float* W       = (const float*)d_in[1];
    const float* bias    = (const float*)d_in[2];
    const float* shift_B = (const float*)d_in[3];
    const float* shift_C = (const float*)d_in[4];
    const float* ssm_k_D = (const float*)d_in[5];
    const float* log_dt  = (const float*)d_in[6];
    const float* log_Ar  = (const float*)d_in[7];
    const float* A_imag  = (const float*)d_in[8];
    const float* B_re    = (const float*)d_in[9];
    const float* B_im    = (const float*)d_in[10];
    float* out = (float*)d_out;

    unsigned short* klin = (unsigned short*)d_ws;   // 32 MB

    gemm_fused<<<dim3(256), 512, 0, stream>>>(W, u, bias, klin);

    expand<<<dim3(DM, 4), 256, 0, stream>>>(klin, shift_B, shift_C, ssm_k_D, log_dt,
                                            log_Ar, A_imag, B_re, B_im, out);
}